// Round 9
// baseline (243.288 us; speedup 1.0000x reference)
//
#include <hip/hip_runtime.h>

#define N_NODES 50000
#define N_EDGES 800000
#define CAP 64
#define NBUCK 782          // ceil(50000/64) buckets of 64 dst nodes
#define NODES_PAD 50048    // NBUCK*64
#define BBLK 256           // edge blocks
#define EPB 3125           // edges per block
#define LOG2E 1.4426950408889634f

typedef unsigned int uint;
typedef unsigned short ushort;
typedef __attribute__((ext_vector_type(2))) float f32x2;
typedef __attribute__((ext_vector_type(4))) float f32x4;
typedef __attribute__((ext_vector_type(8))) short s16x8;

__device__ __forceinline__ f32x2 pk_add(f32x2 a, f32x2 b) {
    f32x2 d;
    asm("v_pk_add_f32 %0, %1, %2" : "=v"(d) : "v"(a), "v"(b));
    return d;
}
__device__ __forceinline__ f32x2 pk_mul(f32x2 a, f32x2 b) {
    f32x2 d;
    asm("v_pk_mul_f32 %0, %1, %2" : "=v"(d) : "v"(a), "v"(b));
    return d;
}
__device__ __forceinline__ f32x2 pk_fma(f32x2 a, f32x2 b, f32x2 c) {
    f32x2 d;
    asm("v_pk_fma_f32 %0, %1, %2, %3" : "=v"(d) : "v"(a), "v"(b), "v"(c));
    return d;
}

__device__ __forceinline__ ushort f2bf(float f) {   // RTNE f32 -> bf16
    uint u = __float_as_uint(f);
    u = (u + 0x7fffu + ((u >> 16) & 1u)) >> 16;
    return (ushort)u;
}
__device__ __forceinline__ float bf_lo(uint u) { return __uint_as_float(u << 16); }
__device__ __forceinline__ float bf_hi(uint u) { return __uint_as_float(u & 0xffff0000u); }

// ---------------- binned adjacency build (buckets of 64 dst nodes) ----------------
__global__ __launch_bounds__(256) void bin_count_kernel(
    const int* __restrict__ dstv, uint* __restrict__ counts)
{
    __shared__ uint hist[NBUCK];
    int tid = threadIdx.x, b = blockIdx.x;
    for (int k = tid; k < NBUCK; k += 256) hist[k] = 0;
    __syncthreads();
    int e0 = b * EPB;
    for (int i = tid; i < EPB; i += 256)
        atomicAdd(&hist[((uint)dstv[e0 + i]) >> 6], 1u);
    __syncthreads();
    for (int k = tid; k < NBUCK; k += 256) counts[k * BBLK + b] = hist[k];
}

// per-bucket local exclusive scan over the 256 block-counts + bucket totals
__global__ __launch_bounds__(256) void scan1_kernel(
    const uint* __restrict__ counts, uint* __restrict__ ofs, uint* __restrict__ bsum)
{
    __shared__ uint wtot[4];
    int tid = threadIdx.x, k = blockIdx.x;
    int lane = tid & 63, wid = tid >> 6;
    uint v = counts[k * 256 + tid];
    uint inc = v;
    #pragma unroll
    for (int o = 1; o < 64; o <<= 1) {
        uint t = __shfl_up(inc, o);
        if (lane >= o) inc += t;
    }
    if (lane == 63) wtot[wid] = inc;
    __syncthreads();
    uint woff = 0;
    for (int w = 0; w < wid; w++) woff += wtot[w];
    uint excl = woff + inc - v;
    ofs[k * 256 + tid] = excl;
    if (tid == 255) bsum[k] = excl + v;
}

// block 0: top-level exclusive scan of 782 bucket totals; blocks 1..16: prep WS=(W@S)*log2e
__global__ __launch_bounds__(256) void scan2_prep_kernel(
    const uint* __restrict__ bsum, uint* __restrict__ bbase,
    const float* __restrict__ W1, const float* __restrict__ as1, const float* __restrict__ ad1,
    const float* __restrict__ W2, const float* __restrict__ as2, const float* __restrict__ ad2,
    float* __restrict__ WS1, float* __restrict__ WS2)
{
    int bid = blockIdx.x;
    int tid = threadIdx.x;
    if (bid == 0) {
        __shared__ uint wtot[4];
        int lane = tid & 63, wid = tid >> 6;
        int base = tid * 4;
        uint v[4];
        #pragma unroll
        for (int j = 0; j < 4; j++) v[j] = (base + j < NBUCK) ? bsum[base + j] : 0u;
        uint s = v[0] + v[1] + v[2] + v[3];
        uint inc = s;
        #pragma unroll
        for (int o = 1; o < 64; o <<= 1) {
            uint t = __shfl_up(inc, o);
            if (lane >= o) inc += t;
        }
        if (lane == 63) wtot[wid] = inc;
        __syncthreads();
        uint woff = 0;
        for (int w = 0; w < wid; w++) woff += wtot[w];
        uint run = woff + inc - s;
        #pragma unroll
        for (int j = 0; j < 4; j++) {
            if (base + j < NBUCK) { bbase[base + j] = run; run += v[j]; }
        }
    } else {
        int idx = (bid - 1) * 256 + tid;      // 0..4095
        if (idx < 2048) {
            int k = idx >> 4, j = idx & 15;
            const float* att = (j < 8) ? as1 : ad1;
            int head = j & 7;
            float s = 0.f;
            #pragma unroll
            for (int c = 0; c < 16; c++)
                s += W1[k * 128 + head * 16 + c] * att[head * 16 + c];
            WS1[idx] = s * LOG2E;
        } else {
            int idx2 = idx - 2048;
            int k = idx2 >> 4, j = idx2 & 15;
            float s = 0.f;
            if (j < 2) {
                const float* att = j ? ad2 : as2;
                for (int c = 0; c < 128; c++) s += W2[k * 128 + c] * att[c];
            }
            WS2[idx2] = s * LOG2E;
        }
    }
}

__global__ __launch_bounds__(256) void bin_scatter_kernel(
    const int* __restrict__ srcv, const int* __restrict__ dstv,
    const uint* __restrict__ ofs, const uint* __restrict__ bbase,
    uint* __restrict__ binned)
{
    __shared__ uint cur[NBUCK];
    int tid = threadIdx.x, b = blockIdx.x;
    for (int k = tid; k < NBUCK; k += 256) cur[k] = ofs[k * BBLK + b] + bbase[k];
    __syncthreads();
    int e0 = b * EPB;
    for (int i = tid; i < EPB; i += 256) {
        int d = dstv[e0 + i], s = srcv[e0 + i];
        uint k = ((uint)d) >> 6;
        uint pos = atomicAdd(&cur[k], 1u);
        binned[pos] = (((uint)d & 63u) << 16) | (uint)s;
    }
}

// block per bucket (64 nodes): LDS-staged ushort lists, dense coalesced writeback
__global__ __launch_bounds__(256) void build_kernel(
    const uint* __restrict__ binned, const uint* __restrict__ ofs,
    const uint* __restrict__ bbase,
    int* __restrict__ deg, ushort* __restrict__ list)
{
    __shared__ uint ldeg[64];
    __shared__ ushort llist[64 * CAP];      // 8 KB
    int tid = threadIdx.x, k = blockIdx.x;
    if (tid < 64) ldeg[tid] = 0;
    __syncthreads();
    uint start = ofs[k * 256] + bbase[k];
    uint end = (k == NBUCK - 1) ? N_EDGES : (ofs[(k + 1) * 256] + bbase[k + 1]);
    for (uint i = start + tid; i < end; i += 256) {
        uint p = binned[i];
        uint nl = (p >> 16) & 63u;
        uint slot = atomicAdd(&ldeg[nl], 1u);
        if (slot < CAP) llist[(nl << 6) + slot] = (ushort)(p & 0xFFFFu);
    }
    __syncthreads();
    int node0 = k << 6;
    if (tid < 64) deg[node0 + tid] = (int)ldeg[tid];
    uint4* d4 = (uint4*)(list + (size_t)node0 * CAP);
    const uint4* s4 = (const uint4*)llist;
    for (int i = tid; i < 64 * CAP * 2 / 16; i += 256) d4[i] = s4[i];
}

// ---------------- MFMA GEMM: h16 = bf16(A @ W) in PACKED [4][N][32] layout ----------------
// Logits fused as 9th tile; layer-1 logits written packed [4][N][2].
template <int HEADS, bool ABF16>
__global__ __launch_bounds__(512) void gemm_mfma_kernel(
    const void* __restrict__ Av, const float* __restrict__ W,
    const float* __restrict__ WS,
    ushort* __restrict__ h16, float* __restrict__ a_src, float* __restrict__ a_dst,
    int nrows)
{
    __shared__ ushort Bf[2304 * 8];   // 36 KB
    int tid = threadIdx.x;
    for (int idx = tid; idx < 2304; idx += 512) {
        int t = idx >> 8;
        int rem = idx & 255;
        int kt = rem >> 6, L = rem & 63;
        int col = L & 15;
        int kb = ((L >> 4) << 3) + (kt << 5);
        ushort tmp[8];
        if (t < 8) {
            #pragma unroll
            for (int j = 0; j < 8; j++)
                tmp[j] = f2bf(W[(size_t)(kb + j) * 128 + (t << 4) + col]);
        } else {
            #pragma unroll
            for (int j = 0; j < 8; j++)
                tmp[j] = f2bf(WS[(kb + j) * 16 + col]);
        }
        uint p0 = (uint)tmp[0] | ((uint)tmp[1] << 16);
        uint p1 = (uint)tmp[2] | ((uint)tmp[3] << 16);
        uint p2 = (uint)tmp[4] | ((uint)tmp[5] << 16);
        uint p3 = (uint)tmp[6] | ((uint)tmp[7] << 16);
        *(uint4*)&Bf[idx * 8] = make_uint4(p0, p1, p2, p3);
    }
    __syncthreads();

    int lane = tid & 63;
    int wv = tid >> 6;
    int row0 = (blockIdx.x * 8 + wv) * 16;
    if (row0 >= nrows) return;

    int m = lane & 15, kg = lane >> 4;
    s16x8 afrag[4];
    if (ABF16) {
        // packed A: fragment kt covers k in [kt*32, kt*32+32) == cg kt of [4][N][32]
        const ushort* abase = (const ushort*)Av + (size_t)(row0 + m) * 32 + (kg << 3);
        #pragma unroll
        for (int kt = 0; kt < 4; kt++)
            afrag[kt] = *(const s16x8*)(abase + (size_t)kt * N_NODES * 32);
    } else {
        const float* arow = (const float*)Av + (size_t)(row0 + m) * 128 + (kg << 3);
        #pragma unroll
        for (int kt = 0; kt < 4; kt++) {
            float4 f0 = *(const float4*)(arow + (kt << 5));
            float4 f1 = *(const float4*)(arow + (kt << 5) + 4);
            union { s16x8 v; ushort us[8]; } uu;
            uu.us[0] = f2bf(f0.x); uu.us[1] = f2bf(f0.y);
            uu.us[2] = f2bf(f0.z); uu.us[3] = f2bf(f0.w);
            uu.us[4] = f2bf(f1.x); uu.us[5] = f2bf(f1.y);
            uu.us[6] = f2bf(f1.z); uu.us[7] = f2bf(f1.w);
            afrag[kt] = uu.v;
        }
    }

    f32x4 acc[9];
    #pragma unroll
    for (int t = 0; t < 9; t++) acc[t] = (f32x4){0.f, 0.f, 0.f, 0.f};
    #pragma unroll
    for (int t = 0; t < 9; t++) {
        #pragma unroll
        for (int kt = 0; kt < 4; kt++) {
            s16x8 b = *(const s16x8*)&Bf[(((t << 2) + kt) * 64 + lane) * 8];
            acc[t] = __builtin_amdgcn_mfma_f32_16x16x32_bf16(afrag[kt], b, acc[t], 0, 0, 0);
        }
    }

    // D layout: col = lane&15, row = (lane>>4)*4 + r   [m89]
    int colw = lane & 15;
    int rbase = row0 + ((lane >> 4) << 2);
    #pragma unroll
    for (int t = 0; t < 8; t++) {
        // packed write: ch = t*16+colw; cg = t>>1; within-cg = ((t&1)<<4)+colw
        size_t base = (size_t)(t >> 1) * N_NODES * 32 + ((t & 1) << 4) + colw;
        #pragma unroll
        for (int r = 0; r < 4; r++)
            h16[base + (size_t)(rbase + r) * 32] = f2bf(acc[t][r]);
    }
    #pragma unroll
    for (int r = 0; r < 4; r++) {
        float v = acc[8][r];
        int row = rbase + r;
        if (HEADS == 8) {
            if (colw < 8)
                a_src[((size_t)(colw >> 1) * N_NODES + row) * 2 + (colw & 1)] = v;
            else {
                int hh = colw - 8;
                a_dst[((size_t)(hh >> 1) * N_NODES + row) * 2 + (hh & 1)] = v;
            }
        } else {
            if (colw == 0)      a_src[row] = v;
            else if (colw == 1) a_dst[row] = v;
        }
    }
}

// ---------------- edge softmax + aggregate, XCD channel-sharded on PACKED h ----------------
// Grid = (N/4 node-groups) x 4 cg; cg = bid&3 -> XCDs {cg, cg+4} (bid%8 round-robin).
// Per-XCD L2 working set: h partition 3.2 MB + packed logits 0.4 MB < 4 MB -> L2-hit gathers.
// Wave = 1 node; 4 lanes/edge x uint4 (16B), 16 edges/round, R<=4 rounds issued upfront.
template <int HEADS, bool ELU, bool OUT16>
__global__ __launch_bounds__(256) void agg_kernel(
    const ushort* __restrict__ h16,          // packed [4][N][32]
    const ushort* __restrict__ list, const int* __restrict__ deg,
    const float* __restrict__ a_src,         // HEADS==8: packed [4][N][2]; HEADS==1: [N]
    const float* __restrict__ a_dst,
    const float* __restrict__ bias, void* __restrict__ outv)
{
    __shared__ float w_lds[4][2][66];
    __shared__ int s_lds[4][64];
    __shared__ float sh_l[4][2];
    int bid = blockIdx.x;
    int cg = bid & 3;
    int lane = threadIdx.x & 63;
    int wv = threadIdx.x >> 6;
    int n = (bid >> 2) * 4 + wv;
    int d = min(deg[n], CAP);
    bool valid = lane < d;
    int s = valid ? (int)list[n * CAP + lane] : 0;
    s_lds[wv][lane] = s << 6;            // byte offset of 64-B packed sub-row

    // softmax for this cg's 2 heads (exp2; WS pre-scaled by log2e). Unnormalized e in LDS.
    if (HEADS == 8) {
        float2 us = *(const float2*)&a_src[((size_t)cg * N_NODES + s) * 2];
        float2 ud = *(const float2*)&a_dst[((size_t)cg * N_NODES + n) * 2];
        float a0 = us.x + ud.x, a1 = us.y + ud.y;
        a0 = fmaxf(a0, 0.2f * a0);       // leaky_relu(0.2)
        a1 = fmaxf(a1, 0.2f * a1);
        float e0 = valid ? exp2f(a0) : 0.f;
        float e1 = valid ? exp2f(a1) : 0.f;
        w_lds[wv][0][lane] = e0;
        w_lds[wv][1][lane] = e1;
        f32x2 ss = {e0, e1};
        #pragma unroll
        for (int mm = 1; mm < 16; mm <<= 1) {
            f32x2 t; t.x = __shfl_xor(ss.x, mm); t.y = __shfl_xor(ss.y, mm);
            ss = pk_add(ss, t);
        }
        if (d > 16) { f32x2 t; t.x = __shfl_xor(ss.x, 16); t.y = __shfl_xor(ss.y, 16); ss = pk_add(ss, t); }
        if (d > 32) { f32x2 t; t.x = __shfl_xor(ss.x, 32); t.y = __shfl_xor(ss.y, 32); ss = pk_add(ss, t); }
        if (lane == 0) { sh_l[wv][0] = ss.x; sh_l[wv][1] = ss.y; }
    } else {
        float a = a_src[s] + a_dst[n];
        a = fmaxf(a, 0.2f * a);
        float e0 = valid ? exp2f(a) : 0.f;
        w_lds[wv][0][lane] = e0;
        w_lds[wv][1][lane] = e0;
        float sh = e0;
        sh += __shfl_xor(sh, 1); sh += __shfl_xor(sh, 2);
        sh += __shfl_xor(sh, 4); sh += __shfl_xor(sh, 8);
        if (d > 16) sh += __shfl_xor(sh, 16);
        if (d > 32) sh += __shfl_xor(sh, 32);
        if (lane == 0) { sh_l[wv][0] = sh; sh_l[wv][1] = sh; }
    }
    // all LDS traffic is wave-private: no barrier needed

    // gather: 4 lanes/edge, 8 ch/lane (uint4 = 16B), 16 edges/round, R<=4 rounds upfront
    int slot = lane >> 2;                // edge sub-slot 0..15
    int lq = lane & 3;                   // 16B chunk: channels [lq*8, lq*8+8) of cg's 32
    int hsel = (HEADS == 8) ? (lq >> 1) : 0;
    const char* hp = (const char*)h16 + (size_t)cg * N_NODES * 64 + (lq << 4);
    int R = (d + 15) >> 4;

    uint4 u[4]; float wk[4];
    #pragma unroll
    for (int r = 0; r < 4; r++) {
        if (r < R) {
            int e = (r << 4) + slot;
            u[r] = *(const uint4*)(hp + s_lds[wv][e]);
            wk[r] = w_lds[wv][hsel][e];
        }
    }
    f32x2 a01 = {0.f, 0.f}, a23 = {0.f, 0.f}, a45 = {0.f, 0.f}, a67 = {0.f, 0.f};
    #pragma unroll
    for (int r = 0; r < 4; r++) {
        if (r < R) {
            f32x2 wp = {wk[r], wk[r]};
            a01 = pk_fma(wp, (f32x2){bf_lo(u[r].x), bf_hi(u[r].x)}, a01);
            a23 = pk_fma(wp, (f32x2){bf_lo(u[r].y), bf_hi(u[r].y)}, a23);
            a45 = pk_fma(wp, (f32x2){bf_lo(u[r].z), bf_hi(u[r].z)}, a45);
            a67 = pk_fma(wp, (f32x2){bf_lo(u[r].w), bf_hi(u[r].w)}, a67);
        }
    }
    // reduce across the 16 edge sub-slots (lane bits 2..5)
    #pragma unroll
    for (int mm = 4; mm < 64; mm <<= 1) {
        f32x2 t;
        t.x = __shfl_xor(a01.x, mm); t.y = __shfl_xor(a01.y, mm); a01 = pk_add(a01, t);
        t.x = __shfl_xor(a23.x, mm); t.y = __shfl_xor(a23.y, mm); a23 = pk_add(a23, t);
        t.x = __shfl_xor(a45.x, mm); t.y = __shfl_xor(a45.y, mm); a45 = pk_add(a45, t);
        t.x = __shfl_xor(a67.x, mm); t.y = __shfl_xor(a67.y, mm); a67 = pk_add(a67, t);
    }
    if (lane < 4) {
        float rv = __builtin_amdgcn_rcpf(sh_l[wv][hsel] + 1e-16f);
        f32x2 rr = {rv, rv};
        a01 = pk_mul(a01, rr); a23 = pk_mul(a23, rr);
        a45 = pk_mul(a45, rr); a67 = pk_mul(a67, rr);
        int ch = (cg << 5) + (lq << 3);  // global channel base
        float4 b0 = *(const float4*)&bias[ch];
        float4 b1 = *(const float4*)&bias[ch + 4];
        float o0 = a01.x + b0.x, o1 = a01.y + b0.y;
        float o2 = a23.x + b0.z, o3 = a23.y + b0.w;
        float o4 = a45.x + b1.x, o5 = a45.y + b1.y;
        float o6 = a67.x + b1.z, o7 = a67.y + b1.w;
        if (ELU) {
            o0 = o0 > 0.f ? o0 : __expf(o0) - 1.f;
            o1 = o1 > 0.f ? o1 : __expf(o1) - 1.f;
            o2 = o2 > 0.f ? o2 : __expf(o2) - 1.f;
            o3 = o3 > 0.f ? o3 : __expf(o3) - 1.f;
            o4 = o4 > 0.f ? o4 : __expf(o4) - 1.f;
            o5 = o5 > 0.f ? o5 : __expf(o5) - 1.f;
            o6 = o6 > 0.f ? o6 : __expf(o6) - 1.f;
            o7 = o7 > 0.f ? o7 : __expf(o7) - 1.f;
        }
        if (OUT16) {
            // packed bf16 out [4][N][32]
            uint4 pk;
            pk.x = (uint)f2bf(o0) | ((uint)f2bf(o1) << 16);
            pk.y = (uint)f2bf(o2) | ((uint)f2bf(o3) << 16);
            pk.z = (uint)f2bf(o4) | ((uint)f2bf(o5) << 16);
            pk.w = (uint)f2bf(o6) | ((uint)f2bf(o7) << 16);
            *(uint4*)((ushort*)outv + ((size_t)cg * N_NODES + n) * 32 + (lq << 3)) = pk;
        } else {
            float* op = (float*)outv + (size_t)n * 128 + ch;
            *(float4*)op = make_float4(o0, o1, o2, o3);
            *(float4*)(op + 4) = make_float4(o4, o5, o6, o7);
        }
    }
}

extern "C" void kernel_launch(void* const* d_in, const int* in_sizes, int n_in,
                              void* d_out, int out_size, void* d_ws, size_t ws_size,
                              hipStream_t stream)
{
    (void)in_sizes; (void)n_in; (void)out_size; (void)ws_size;
    const float* x   = (const float*)d_in[0];
    const int*   ei  = (const int*)d_in[1];
    const float* W1  = (const float*)d_in[2];
    const float* as1 = (const float*)d_in[3];
    const float* ad1 = (const float*)d_in[4];
    const float* b1  = (const float*)d_in[5];
    const float* W2  = (const float*)d_in[6];
    const float* as2 = (const float*)d_in[7];
    const float* ad2 = (const float*)d_in[8];
    const float* b2  = (const float*)d_in[9];
    float* out = (float*)d_out;
    const int* srcv = ei;
    const int* dstv = ei + N_EDGES;

    char* ws = (char*)d_ws;
    size_t off = 0;
    auto alloc = [&](size_t bytes) {
        void* p = ws + off;
        off += (bytes + 255) & ~(size_t)255;
        return p;
    };
    ushort* h1_16 = (ushort*)alloc((size_t)N_NODES * 128 * 2);   // packed [4][N][32]
    ushort* h2_16 = (ushort*)alloc((size_t)N_NODES * 128 * 2);   // packed [4][N][32]
    ushort* h1b   = (ushort*)alloc((size_t)N_NODES * 128 * 2);   // packed bf16 inter-layer act
    float*  asrc1 = (float*)alloc((size_t)N_NODES * 8 * 4);      // packed [4][N][2]
    float*  adst1 = (float*)alloc((size_t)N_NODES * 8 * 4);      // packed [4][N][2]
    float*  asrc2 = (float*)alloc((size_t)N_NODES * 4);
    float*  adst2 = (float*)alloc((size_t)N_NODES * 4);
    int*    degp  = (int*)alloc((size_t)NODES_PAD * 4);
    ushort* list  = (ushort*)alloc((size_t)NODES_PAD * CAP * 2);
    float*  WS1   = (float*)alloc(128 * 16 * 4);
    float*  WS2   = (float*)alloc(128 * 16 * 4);
    // bin scratch aliases into h1b (fully consumed before agg1 writes h1b)
    uint* binned = (uint*)h1b;                       // 3.2 MB
    uint* counts = binned + N_EDGES;                 // 800 KB (NBUCK*BBLK)
    uint* ofsp   = counts + NBUCK * BBLK;            // 800 KB
    uint* bsum   = ofsp + NBUCK * BBLK;              // ~3 KB
    uint* bbase  = bsum + NBUCK;                     // ~3 KB

    const int AG = (N_NODES / 4) * 4;              // 50000 blocks (node-group x 4 cg)
    const int GB = (N_NODES / 16 + 7) / 8;         // 391 blocks of 8 waves

    bin_count_kernel<<<BBLK, 256, 0, stream>>>(dstv, counts);
    scan1_kernel<<<NBUCK, 256, 0, stream>>>(counts, ofsp, bsum);
    scan2_prep_kernel<<<17, 256, 0, stream>>>(bsum, bbase, W1, as1, ad1, W2, as2, ad2, WS1, WS2);
    bin_scatter_kernel<<<BBLK, 256, 0, stream>>>(srcv, dstv, ofsp, bbase, binned);
    build_kernel<<<NBUCK, 256, 0, stream>>>(binned, ofsp, bbase, degp, list);

    gemm_mfma_kernel<8, false><<<GB, 512, 0, stream>>>(x, W1, WS1, h1_16, asrc1, adst1, N_NODES);
    agg_kernel<8, true, true><<<AG, 256, 0, stream>>>(h1_16, list, degp, asrc1, adst1, b1, h1b);

    gemm_mfma_kernel<1, true><<<GB, 512, 0, stream>>>(h1b, W2, WS2, h2_16, asrc2, adst2, N_NODES);
    agg_kernel<1, false, false><<<AG, 256, 0, stream>>>(h2_16, list, degp, asrc2, adst2, b2, out);
}

// Round 10
// 239.420 us; speedup vs baseline: 1.0162x; 1.0162x over previous
//
#include <hip/hip_runtime.h>

#define N_NODES 50000
#define N_EDGES 800000
#define CAP 64
#define NBUCK 782          // ceil(50000/64) buckets of 64 dst nodes
#define NODES_PAD 50048    // NBUCK*64
#define BBLK 256           // edge blocks
#define EPB 3125           // edges per block
#define LOG2E 1.4426950408889634f

typedef unsigned int uint;
typedef unsigned short ushort;
typedef __attribute__((ext_vector_type(2))) float f32x2;
typedef __attribute__((ext_vector_type(4))) float f32x4;
typedef __attribute__((ext_vector_type(8))) short s16x8;

__device__ __forceinline__ f32x2 pk_add(f32x2 a, f32x2 b) {
    f32x2 d;
    asm("v_pk_add_f32 %0, %1, %2" : "=v"(d) : "v"(a), "v"(b));
    return d;
}
__device__ __forceinline__ f32x2 pk_fma(f32x2 a, f32x2 b, f32x2 c) {
    f32x2 d;
    asm("v_pk_fma_f32 %0, %1, %2, %3" : "=v"(d) : "v"(a), "v"(b), "v"(c));
    return d;
}

__device__ __forceinline__ ushort f2bf(float f) {   // RTNE f32 -> bf16
    uint u = __float_as_uint(f);
    u = (u + 0x7fffu + ((u >> 16) & 1u)) >> 16;
    return (ushort)u;
}
__device__ __forceinline__ float bf_lo(uint u) { return __uint_as_float(u << 16); }
__device__ __forceinline__ float bf_hi(uint u) { return __uint_as_float(u & 0xffff0000u); }

// ---------------- binned adjacency build (buckets of 64 dst nodes) ----------------
__global__ __launch_bounds__(256) void bin_count_kernel(
    const int* __restrict__ dstv, uint* __restrict__ counts)
{
    __shared__ uint hist[NBUCK];
    int tid = threadIdx.x, b = blockIdx.x;
    for (int k = tid; k < NBUCK; k += 256) hist[k] = 0;
    __syncthreads();
    int e0 = b * EPB;
    for (int i = tid; i < EPB; i += 256)
        atomicAdd(&hist[((uint)dstv[e0 + i]) >> 6], 1u);
    __syncthreads();
    for (int k = tid; k < NBUCK; k += 256) counts[k * BBLK + b] = hist[k];
}

// per-bucket local exclusive scan over the 256 block-counts + bucket totals
__global__ __launch_bounds__(256) void scan1_kernel(
    const uint* __restrict__ counts, uint* __restrict__ ofs, uint* __restrict__ bsum)
{
    __shared__ uint wtot[4];
    int tid = threadIdx.x, k = blockIdx.x;
    int lane = tid & 63, wid = tid >> 6;
    uint v = counts[k * 256 + tid];
    uint inc = v;
    #pragma unroll
    for (int o = 1; o < 64; o <<= 1) {
        uint t = __shfl_up(inc, o);
        if (lane >= o) inc += t;
    }
    if (lane == 63) wtot[wid] = inc;
    __syncthreads();
    uint woff = 0;
    for (int w = 0; w < wid; w++) woff += wtot[w];
    uint excl = woff + inc - v;
    ofs[k * 256 + tid] = excl;
    if (tid == 255) bsum[k] = excl + v;
}

// block 0: top-level exclusive scan of 782 bucket totals; blocks 1..16: prep WS=(W@S)*log2e
__global__ __launch_bounds__(256) void scan2_prep_kernel(
    const uint* __restrict__ bsum, uint* __restrict__ bbase,
    const float* __restrict__ W1, const float* __restrict__ as1, const float* __restrict__ ad1,
    const float* __restrict__ W2, const float* __restrict__ as2, const float* __restrict__ ad2,
    float* __restrict__ WS1, float* __restrict__ WS2)
{
    int bid = blockIdx.x;
    int tid = threadIdx.x;
    if (bid == 0) {
        __shared__ uint wtot[4];
        int lane = tid & 63, wid = tid >> 6;
        int base = tid * 4;
        uint v[4];
        #pragma unroll
        for (int j = 0; j < 4; j++) v[j] = (base + j < NBUCK) ? bsum[base + j] : 0u;
        uint s = v[0] + v[1] + v[2] + v[3];
        uint inc = s;
        #pragma unroll
        for (int o = 1; o < 64; o <<= 1) {
            uint t = __shfl_up(inc, o);
            if (lane >= o) inc += t;
        }
        if (lane == 63) wtot[wid] = inc;
        __syncthreads();
        uint woff = 0;
        for (int w = 0; w < wid; w++) woff += wtot[w];
        uint run = woff + inc - s;
        #pragma unroll
        for (int j = 0; j < 4; j++) {
            if (base + j < NBUCK) { bbase[base + j] = run; run += v[j]; }
        }
    } else {
        int idx = (bid - 1) * 256 + tid;      // 0..4095
        if (idx < 2048) {
            int k = idx >> 4, j = idx & 15;
            const float* att = (j < 8) ? as1 : ad1;
            int head = j & 7;
            float s = 0.f;
            #pragma unroll
            for (int c = 0; c < 16; c++)
                s += W1[k * 128 + head * 16 + c] * att[head * 16 + c];
            WS1[idx] = s * LOG2E;
        } else {
            int idx2 = idx - 2048;
            int k = idx2 >> 4, j = idx2 & 15;
            float s = 0.f;
            if (j < 2) {
                const float* att = j ? ad2 : as2;
                for (int c = 0; c < 128; c++) s += W2[k * 128 + c] * att[c];
            }
            WS2[idx2] = s * LOG2E;
        }
    }
}

__global__ __launch_bounds__(256) void bin_scatter_kernel(
    const int* __restrict__ srcv, const int* __restrict__ dstv,
    const uint* __restrict__ ofs, const uint* __restrict__ bbase,
    uint* __restrict__ binned)
{
    __shared__ uint cur[NBUCK];
    int tid = threadIdx.x, b = blockIdx.x;
    for (int k = tid; k < NBUCK; k += 256) cur[k] = ofs[k * BBLK + b] + bbase[k];
    __syncthreads();
    int e0 = b * EPB;
    for (int i = tid; i < EPB; i += 256) {
        int d = dstv[e0 + i], s = srcv[e0 + i];
        uint k = ((uint)d) >> 6;
        uint pos = atomicAdd(&cur[k], 1u);
        binned[pos] = (((uint)d & 63u) << 16) | (uint)s;
    }
}

// block per bucket (64 nodes): LDS-staged ushort lists (zero-padded), coalesced writeback
__global__ __launch_bounds__(256) void build_kernel(
    const uint* __restrict__ binned, const uint* __restrict__ ofs,
    const uint* __restrict__ bbase,
    int* __restrict__ deg, ushort* __restrict__ list)
{
    __shared__ uint ldeg[64];
    __shared__ ushort llist[64 * CAP];      // 8 KB
    int tid = threadIdx.x, k = blockIdx.x;
    if (tid < 64) ldeg[tid] = 0;
    for (int i = tid; i < 64 * CAP / 2; i += 256) ((uint*)llist)[i] = 0;  // zero-pad
    __syncthreads();
    uint start = ofs[k * 256] + bbase[k];
    uint end = (k == NBUCK - 1) ? N_EDGES : (ofs[(k + 1) * 256] + bbase[k + 1]);
    for (uint i = start + tid; i < end; i += 256) {
        uint p = binned[i];
        uint nl = (p >> 16) & 63u;
        uint slot = atomicAdd(&ldeg[nl], 1u);
        if (slot < CAP) llist[(nl << 6) + slot] = (ushort)(p & 0xFFFFu);
    }
    __syncthreads();
    int node0 = k << 6;
    if (tid < 64) deg[node0 + tid] = (int)ldeg[tid];
    uint4* d4 = (uint4*)(list + (size_t)node0 * CAP);
    const uint4* s4 = (const uint4*)llist;
    for (int i = tid; i < 64 * CAP * 2 / 16; i += 256) d4[i] = s4[i];
}

// ---------------- MFMA GEMM: h16 = bf16(A @ W) in PACKED [4][N][32] layout ----------------
// Logits fused as 9th tile; layer-1 logits written packed [4][N][2].
template <int HEADS, bool ABF16>
__global__ __launch_bounds__(512) void gemm_mfma_kernel(
    const void* __restrict__ Av, const float* __restrict__ W,
    const float* __restrict__ WS,
    ushort* __restrict__ h16, float* __restrict__ a_src, float* __restrict__ a_dst,
    int nrows)
{
    __shared__ ushort Bf[2304 * 8];   // 36 KB
    int tid = threadIdx.x;
    for (int idx = tid; idx < 2304; idx += 512) {
        int t = idx >> 8;
        int rem = idx & 255;
        int kt = rem >> 6, L = rem & 63;
        int col = L & 15;
        int kb = ((L >> 4) << 3) + (kt << 5);
        ushort tmp[8];
        if (t < 8) {
            #pragma unroll
            for (int j = 0; j < 8; j++)
                tmp[j] = f2bf(W[(size_t)(kb + j) * 128 + (t << 4) + col]);
        } else {
            #pragma unroll
            for (int j = 0; j < 8; j++)
                tmp[j] = f2bf(WS[(kb + j) * 16 + col]);
        }
        uint p0 = (uint)tmp[0] | ((uint)tmp[1] << 16);
        uint p1 = (uint)tmp[2] | ((uint)tmp[3] << 16);
        uint p2 = (uint)tmp[4] | ((uint)tmp[5] << 16);
        uint p3 = (uint)tmp[6] | ((uint)tmp[7] << 16);
        *(uint4*)&Bf[idx * 8] = make_uint4(p0, p1, p2, p3);
    }
    __syncthreads();

    int lane = tid & 63;
    int wv = tid >> 6;
    int row0 = (blockIdx.x * 8 + wv) * 16;
    if (row0 >= nrows) return;

    int m = lane & 15, kg = lane >> 4;
    s16x8 afrag[4];
    if (ABF16) {
        // packed A: fragment kt covers k in [kt*32, kt*32+32) == cg kt of [4][N][32]
        const ushort* abase = (const ushort*)Av + (size_t)(row0 + m) * 32 + (kg << 3);
        #pragma unroll
        for (int kt = 0; kt < 4; kt++)
            afrag[kt] = *(const s16x8*)(abase + (size_t)kt * N_NODES * 32);
    } else {
        const float* arow = (const float*)Av + (size_t)(row0 + m) * 128 + (kg << 3);
        #pragma unroll
        for (int kt = 0; kt < 4; kt++) {
            float4 f0 = *(const float4*)(arow + (kt << 5));
            float4 f1 = *(const float4*)(arow + (kt << 5) + 4);
            union { s16x8 v; ushort us[8]; } uu;
            uu.us[0] = f2bf(f0.x); uu.us[1] = f2bf(f0.y);
            uu.us[2] = f2bf(f0.z); uu.us[3] = f2bf(f0.w);
            uu.us[4] = f2bf(f1.x); uu.us[5] = f2bf(f1.y);
            uu.us[6] = f2bf(f1.z); uu.us[7] = f2bf(f1.w);
            afrag[kt] = uu.v;
        }
    }

    f32x4 acc[9];
    #pragma unroll
    for (int t = 0; t < 9; t++) acc[t] = (f32x4){0.f, 0.f, 0.f, 0.f};
    #pragma unroll
    for (int t = 0; t < 9; t++) {
        #pragma unroll
        for (int kt = 0; kt < 4; kt++) {
            s16x8 b = *(const s16x8*)&Bf[(((t << 2) + kt) * 64 + lane) * 8];
            acc[t] = __builtin_amdgcn_mfma_f32_16x16x32_bf16(afrag[kt], b, acc[t], 0, 0, 0);
        }
    }

    // D layout: col = lane&15, row = (lane>>4)*4 + r   [m89]
    int colw = lane & 15;
    int rbase = row0 + ((lane >> 4) << 2);
    #pragma unroll
    for (int t = 0; t < 8; t++) {
        // packed write: ch = t*16+colw; cg = t>>1; within-cg = ((t&1)<<4)+colw
        size_t base = (size_t)(t >> 1) * N_NODES * 32 + ((t & 1) << 4) + colw;
        #pragma unroll
        for (int r = 0; r < 4; r++)
            h16[base + (size_t)(rbase + r) * 32] = f2bf(acc[t][r]);
    }
    #pragma unroll
    for (int r = 0; r < 4; r++) {
        float v = acc[8][r];
        int row = rbase + r;
        if (HEADS == 8) {
            if (colw < 8)
                a_src[((size_t)(colw >> 1) * N_NODES + row) * 2 + (colw & 1)] = v;
            else {
                int hh = colw - 8;
                a_dst[((size_t)(hh >> 1) * N_NODES + row) * 2 + (hh & 1)] = v;
            }
        } else {
            if (colw == 0)      a_src[row] = v;
            else if (colw == 1) a_dst[row] = v;
        }
    }
}

// ---------------- edge softmax + aggregate, XCD channel-sharded, 16 nodes/block ----------------
// Grid = (N/16) x 4 cg; cg = bid&3 -> XCDs {cg, cg+4} (bid%8 round-robin).
// Per-XCD L2 working set: h partition 3.2 MB + packed logits 0.4 MB < 4 MB -> L2-hit gathers.
// Phase1: stage 16 lists (coalesced). Phase2: wave does softmax for 4 nodes (normalized w->LDS).
// Phase3: wave gathers 4 nodes, 8 lanes/edge x uint2, 16 loads issued upfront.
template <int HEADS, bool ELU, bool OUT16>
__global__ __launch_bounds__(256) void agg_kernel(
    const ushort* __restrict__ h16,          // packed [4][N][32]
    const ushort* __restrict__ list, const int* __restrict__ deg,
    const float* __restrict__ a_src,         // HEADS==8: packed [4][N][2]; HEADS==1: [N]
    const float* __restrict__ a_dst,
    const float* __restrict__ bias, void* __restrict__ outv)
{
    __shared__ ushort slist[16][64];   // 2 KB
    __shared__ f32x2 wlds[16][64];     // 8 KB (normalized weights, 2 heads)
    __shared__ int degl[16];
    int bid = blockIdx.x;
    int cg = bid & 3;
    int ng = bid >> 2;
    int tid = threadIdx.x;
    int lane = tid & 63;
    int wv = tid >> 6;

    // phase 1: stage lists + degrees (coalesced)
    ((uint2*)slist)[tid] = ((const uint2*)(list + (size_t)ng * 16 * CAP))[tid];
    if (tid < 16) degl[tid] = min(deg[ng * 16 + tid], CAP);
    __syncthreads();

    // phase 2: softmax, 4 nodes per wave; normalized weights into wlds
    #pragma unroll
    for (int i = 0; i < 4; i++) {
        int ln = (wv << 2) + i;
        int n = ng * 16 + ln;
        int d = degl[ln];
        bool valid = lane < d;
        int s = (int)slist[ln][lane];
        float e0, e1;
        if (HEADS == 8) {
            float2 us = *(const float2*)&a_src[((size_t)cg * N_NODES + s) * 2];
            float2 ud = *(const float2*)&a_dst[((size_t)cg * N_NODES + n) * 2];
            float A0 = us.x + ud.x, A1 = us.y + ud.y;
            A0 = fmaxf(A0, 0.2f * A0);           // leaky_relu(0.2), log2e pre-folded
            A1 = fmaxf(A1, 0.2f * A1);
            e0 = valid ? exp2f(A0) : 0.f;
            e1 = valid ? exp2f(A1) : 0.f;
        } else {
            float A = a_src[s] + a_dst[n];
            A = fmaxf(A, 0.2f * A);
            e0 = valid ? exp2f(A) : 0.f;
            e1 = e0;
        }
        f32x2 ss = {e0, e1};
        #pragma unroll
        for (int mm = 1; mm < 16; mm <<= 1) {
            f32x2 t; t.x = __shfl_xor(ss.x, mm); t.y = __shfl_xor(ss.y, mm);
            ss = pk_add(ss, t);
        }
        if (d > 16) { f32x2 t; t.x = __shfl_xor(ss.x, 16); t.y = __shfl_xor(ss.y, 16); ss = pk_add(ss, t); }
        if (d > 32) { f32x2 t; t.x = __shfl_xor(ss.x, 32); t.y = __shfl_xor(ss.y, 32); ss = pk_add(ss, t); }
        float r0 = __builtin_amdgcn_rcpf(ss.x + 1e-16f);
        float r1 = (HEADS == 8) ? __builtin_amdgcn_rcpf(ss.y + 1e-16f) : r0;
        wlds[ln][lane] = (f32x2){e0 * r0, e1 * r1};
    }
    __syncthreads();

    // phase 3: gather + FMA. 8 lanes/edge, 4 ch/lane (uint2), 8 edges/round.
    int slot = lane >> 3;              // edge sub-slot 0..7
    int lq = lane & 7;                 // 8B chunk: cg-local channels [lq*4, lq*4+4)
    int hsel = lq >> 2;                // head within cg pair
    const char* hp = (const char*)h16 + (size_t)cg * N_NODES * 64 + (lq << 3);
    int dv[4];
    #pragma unroll
    for (int i = 0; i < 4; i++) dv[i] = degl[(wv << 2) + i];

    uint2 u[4][4];
    #pragma unroll
    for (int i = 0; i < 4; i++) {
        int ln = (wv << 2) + i;
        #pragma unroll
        for (int r = 0; r < 4; r++) {
            if ((r << 3) < dv[i]) {
                int e = (r << 3) + slot;
                u[i][r] = *(const uint2*)(hp + ((int)slist[ln][e] << 6));
            }
        }
    }
    f32x2 a01[4], a23[4];
    #pragma unroll
    for (int i = 0; i < 4; i++) { a01[i] = (f32x2){0.f, 0.f}; a23[i] = (f32x2){0.f, 0.f}; }
    #pragma unroll
    for (int i = 0; i < 4; i++) {
        int ln = (wv << 2) + i;
        #pragma unroll
        for (int r = 0; r < 4; r++) {
            if ((r << 3) < dv[i]) {
                int e = (r << 3) + slot;
                f32x2 wpair = wlds[ln][e];           // b64 broadcast among 8 lanes
                float w = hsel ? wpair.y : wpair.x;
                f32x2 wp = {w, w};
                a01[i] = pk_fma(wp, (f32x2){bf_lo(u[i][r].x), bf_hi(u[i][r].x)}, a01[i]);
                a23[i] = pk_fma(wp, (f32x2){bf_lo(u[i][r].y), bf_hi(u[i][r].y)}, a23[i]);
            }
        }
        if (dv[i] > 32) {                            // rare tail (P ~ 3e-5)
            for (int e = 32 + slot; e < dv[i]; e += 8) {
                uint2 uu = *(const uint2*)(hp + ((int)slist[ln][e] << 6));
                f32x2 wpair = wlds[ln][e];
                float w = hsel ? wpair.y : wpair.x;
                f32x2 wp = {w, w};
                a01[i] = pk_fma(wp, (f32x2){bf_lo(uu.x), bf_hi(uu.x)}, a01[i]);
                a23[i] = pk_fma(wp, (f32x2){bf_lo(uu.y), bf_hi(uu.y)}, a23[i]);
            }
        }
    }
    // reduce across the 8 edge sub-slots (lane bits 3..5)
    #pragma unroll
    for (int mm = 8; mm < 64; mm <<= 1) {
        #pragma unroll
        for (int i = 0; i < 4; i++) {
            f32x2 t;
            t.x = __shfl_xor(a01[i].x, mm); t.y = __shfl_xor(a01[i].y, mm); a01[i] = pk_add(a01[i], t);
            t.x = __shfl_xor(a23[i].x, mm); t.y = __shfl_xor(a23[i].y, mm); a23[i] = pk_add(a23[i], t);
        }
    }
    if (lane < 8) {
        int ch = (cg << 5) + (lq << 2);
        float4 bv = *(const float4*)&bias[ch];
        #pragma unroll
        for (int i = 0; i < 4; i++) {
            int n = ng * 16 + (wv << 2) + i;
            float o0 = a01[i].x + bv.x, o1 = a01[i].y + bv.y;
            float o2 = a23[i].x + bv.z, o3 = a23[i].y + bv.w;
            if (ELU) {
                o0 = o0 > 0.f ? o0 : __expf(o0) - 1.f;
                o1 = o1 > 0.f ? o1 : __expf(o1) - 1.f;
                o2 = o2 > 0.f ? o2 : __expf(o2) - 1.f;
                o3 = o3 > 0.f ? o3 : __expf(o3) - 1.f;
            }
            if (OUT16) {
                uint2 pk;
                pk.x = (uint)f2bf(o0) | ((uint)f2bf(o1) << 16);
                pk.y = (uint)f2bf(o2) | ((uint)f2bf(o3) << 16);
                *(uint2*)((ushort*)outv + ((size_t)cg * N_NODES + n) * 32 + (lq << 2)) = pk;
            } else {
                *(float4*)((float*)outv + (size_t)n * 128 + ch) = make_float4(o0, o1, o2, o3);
            }
        }
    }
}

extern "C" void kernel_launch(void* const* d_in, const int* in_sizes, int n_in,
                              void* d_out, int out_size, void* d_ws, size_t ws_size,
                              hipStream_t stream)
{
    (void)in_sizes; (void)n_in; (void)out_size; (void)ws_size;
    const float* x   = (const float*)d_in[0];
    const int*   ei  = (const int*)d_in[1];
    const float* W1  = (const float*)d_in[2];
    const float* as1 = (const float*)d_in[3];
    const float* ad1 = (const float*)d_in[4];
    const float* b1  = (const float*)d_in[5];
    const float* W2  = (const float*)d_in[6];
    const float* as2 = (const float*)d_in[7];
    const float* ad2 = (const float*)d_in[8];
    const float* b2  = (const float*)d_in[9];
    float* out = (float*)d_out;
    const int* srcv = ei;
    const int* dstv = ei + N_EDGES;

    char* ws = (char*)d_ws;
    size_t off = 0;
    auto alloc = [&](size_t bytes) {
        void* p = ws + off;
        off += (bytes + 255) & ~(size_t)255;
        return p;
    };
    ushort* h1_16 = (ushort*)alloc((size_t)N_NODES * 128 * 2);   // packed [4][N][32]
    ushort* h2_16 = (ushort*)alloc((size_t)N_NODES * 128 * 2);   // packed [4][N][32]
    ushort* h1b   = (ushort*)alloc((size_t)N_NODES * 128 * 2);   // packed bf16 inter-layer act
    float*  asrc1 = (float*)alloc((size_t)N_NODES * 8 * 4);      // packed [4][N][2]
    float*  adst1 = (float*)alloc((size_t)N_NODES * 8 * 4);      // packed [4][N][2]
    float*  asrc2 = (float*)alloc((size_t)N_NODES * 4);
    float*  adst2 = (float*)alloc((size_t)N_NODES * 4);
    int*    degp  = (int*)alloc((size_t)NODES_PAD * 4);
    ushort* list  = (ushort*)alloc((size_t)NODES_PAD * CAP * 2);
    float*  WS1   = (float*)alloc(128 * 16 * 4);
    float*  WS2   = (float*)alloc(128 * 16 * 4);
    // bin scratch aliases into h1b (fully consumed before agg1 writes h1b)
    uint* binned = (uint*)h1b;                       // 3.2 MB
    uint* counts = binned + N_EDGES;                 // 800 KB (NBUCK*BBLK)
    uint* ofsp   = counts + NBUCK * BBLK;            // 800 KB
    uint* bsum   = ofsp + NBUCK * BBLK;              // ~3 KB
    uint* bbase  = bsum + NBUCK;                     // ~3 KB

    const int AG = (N_NODES / 16) * 4;             // 12500 blocks (node-group x 4 cg)
    const int GB = (N_NODES / 16 + 7) / 8;         // 391 blocks of 8 waves

    bin_count_kernel<<<BBLK, 256, 0, stream>>>(dstv, counts);
    scan1_kernel<<<NBUCK, 256, 0, stream>>>(counts, ofsp, bsum);
    scan2_prep_kernel<<<17, 256, 0, stream>>>(bsum, bbase, W1, as1, ad1, W2, as2, ad2, WS1, WS2);
    bin_scatter_kernel<<<BBLK, 256, 0, stream>>>(srcv, dstv, ofsp, bbase, binned);
    build_kernel<<<NBUCK, 256, 0, stream>>>(binned, ofsp, bbase, degp, list);

    gemm_mfma_kernel<8, false><<<GB, 512, 0, stream>>>(x, W1, WS1, h1_16, asrc1, adst1, N_NODES);
    agg_kernel<8, true, true><<<AG, 256, 0, stream>>>(h1_16, list, degp, asrc1, adst1, b1, h1b);

    gemm_mfma_kernel<1, true><<<GB, 512, 0, stream>>>(h1b, W2, WS2, h2_16, asrc2, adst2, N_NODES);
    agg_kernel<1, false, false><<<AG, 256, 0, stream>>>(h2_16, list, degp, asrc2, adst2, b2, out);
}

// Round 11
// 124.064 us; speedup vs baseline: 1.9610x; 1.9298x over previous
//
#include <hip/hip_runtime.h>

#define N_NODES 50000
#define N_EDGES 800000
#define CAP 64
#define NBUCK 782          // ceil(50000/64) buckets of 64 dst nodes
#define NODES_PAD 50048    // NBUCK*64
#define BBLK 256           // edge blocks
#define EPB 3125           // edges per block
#define LOG2E 1.4426950408889634f

typedef unsigned int uint;
typedef unsigned short ushort;
typedef __attribute__((ext_vector_type(2))) float f32x2;
typedef __attribute__((ext_vector_type(4))) float f32x4;
typedef __attribute__((ext_vector_type(8))) short s16x8;

__device__ __forceinline__ f32x2 pk_add(f32x2 a, f32x2 b) {
    f32x2 d;
    asm("v_pk_add_f32 %0, %1, %2" : "=v"(d) : "v"(a), "v"(b));
    return d;
}
__device__ __forceinline__ f32x2 pk_mul(f32x2 a, f32x2 b) {
    f32x2 d;
    asm("v_pk_mul_f32 %0, %1, %2" : "=v"(d) : "v"(a), "v"(b));
    return d;
}
__device__ __forceinline__ f32x2 pk_fma(f32x2 a, f32x2 b, f32x2 c) {
    f32x2 d;
    asm("v_pk_fma_f32 %0, %1, %2, %3" : "=v"(d) : "v"(a), "v"(b), "v"(c));
    return d;
}

__device__ __forceinline__ ushort f2bf(float f) {   // RTNE f32 -> bf16
    uint u = __float_as_uint(f);
    u = (u + 0x7fffu + ((u >> 16) & 1u)) >> 16;
    return (ushort)u;
}
__device__ __forceinline__ float bf_lo(uint u) { return __uint_as_float(u << 16); }
__device__ __forceinline__ float bf_hi(uint u) { return __uint_as_float(u & 0xffff0000u); }

// ---------------- binned adjacency build (buckets of 64 dst nodes) ----------------
__global__ __launch_bounds__(256) void bin_count_kernel(
    const int* __restrict__ dstv, uint* __restrict__ counts)
{
    __shared__ uint hist[NBUCK];
    int tid = threadIdx.x, b = blockIdx.x;
    for (int k = tid; k < NBUCK; k += 256) hist[k] = 0;
    __syncthreads();
    int e0 = b * EPB;
    for (int i = tid; i < EPB; i += 256)
        atomicAdd(&hist[((uint)dstv[e0 + i]) >> 6], 1u);
    __syncthreads();
    for (int k = tid; k < NBUCK; k += 256) counts[k * BBLK + b] = hist[k];
}

// per-bucket local exclusive scan over the 256 block-counts + bucket totals
__global__ __launch_bounds__(256) void scan1_kernel(
    const uint* __restrict__ counts, uint* __restrict__ ofs, uint* __restrict__ bsum)
{
    __shared__ uint wtot[4];
    int tid = threadIdx.x, k = blockIdx.x;
    int lane = tid & 63, wid = tid >> 6;
    uint v = counts[k * 256 + tid];
    uint inc = v;
    #pragma unroll
    for (int o = 1; o < 64; o <<= 1) {
        uint t = __shfl_up(inc, o);
        if (lane >= o) inc += t;
    }
    if (lane == 63) wtot[wid] = inc;
    __syncthreads();
    uint woff = 0;
    for (int w = 0; w < wid; w++) woff += wtot[w];
    uint excl = woff + inc - v;
    ofs[k * 256 + tid] = excl;
    if (tid == 255) bsum[k] = excl + v;
}

// block 0: top-level exclusive scan of 782 bucket totals; blocks 1..16: prep WS=(W@S)*log2e
__global__ __launch_bounds__(256) void scan2_prep_kernel(
    const uint* __restrict__ bsum, uint* __restrict__ bbase,
    const float* __restrict__ W1, const float* __restrict__ as1, const float* __restrict__ ad1,
    const float* __restrict__ W2, const float* __restrict__ as2, const float* __restrict__ ad2,
    float* __restrict__ WS1, float* __restrict__ WS2)
{
    int bid = blockIdx.x;
    int tid = threadIdx.x;
    if (bid == 0) {
        __shared__ uint wtot[4];
        int lane = tid & 63, wid = tid >> 6;
        int base = tid * 4;
        uint v[4];
        #pragma unroll
        for (int j = 0; j < 4; j++) v[j] = (base + j < NBUCK) ? bsum[base + j] : 0u;
        uint s = v[0] + v[1] + v[2] + v[3];
        uint inc = s;
        #pragma unroll
        for (int o = 1; o < 64; o <<= 1) {
            uint t = __shfl_up(inc, o);
            if (lane >= o) inc += t;
        }
        if (lane == 63) wtot[wid] = inc;
        __syncthreads();
        uint woff = 0;
        for (int w = 0; w < wid; w++) woff += wtot[w];
        uint run = woff + inc - s;
        #pragma unroll
        for (int j = 0; j < 4; j++) {
            if (base + j < NBUCK) { bbase[base + j] = run; run += v[j]; }
        }
    } else {
        int idx = (bid - 1) * 256 + tid;      // 0..4095
        if (idx < 2048) {
            int k = idx >> 4, j = idx & 15;
            const float* att = (j < 8) ? as1 : ad1;
            int head = j & 7;
            float s = 0.f;
            #pragma unroll
            for (int c = 0; c < 16; c++)
                s += W1[k * 128 + head * 16 + c] * att[head * 16 + c];
            WS1[idx] = s * LOG2E;
        } else {
            int idx2 = idx - 2048;
            int k = idx2 >> 4, j = idx2 & 15;
            float s = 0.f;
            if (j < 2) {
                const float* att = j ? ad2 : as2;
                for (int c = 0; c < 128; c++) s += W2[k * 128 + c] * att[c];
            }
            WS2[idx2] = s * LOG2E;
        }
    }
}

__global__ __launch_bounds__(256) void bin_scatter_kernel(
    const int* __restrict__ srcv, const int* __restrict__ dstv,
    const uint* __restrict__ ofs, const uint* __restrict__ bbase,
    uint* __restrict__ binned)
{
    __shared__ uint cur[NBUCK];
    int tid = threadIdx.x, b = blockIdx.x;
    for (int k = tid; k < NBUCK; k += 256) cur[k] = ofs[k * BBLK + b] + bbase[k];
    __syncthreads();
    int e0 = b * EPB;
    for (int i = tid; i < EPB; i += 256) {
        int d = dstv[e0 + i], s = srcv[e0 + i];
        uint k = ((uint)d) >> 6;
        uint pos = atomicAdd(&cur[k], 1u);
        binned[pos] = (((uint)d & 63u) << 16) | (uint)s;
    }
}

// block per bucket (64 nodes): LDS-staged ushort lists (zero-padded), coalesced writeback
__global__ __launch_bounds__(256) void build_kernel(
    const uint* __restrict__ binned, const uint* __restrict__ ofs,
    const uint* __restrict__ bbase,
    int* __restrict__ deg, ushort* __restrict__ list)
{
    __shared__ uint ldeg[64];
    __shared__ ushort llist[64 * CAP];      // 8 KB
    int tid = threadIdx.x, k = blockIdx.x;
    if (tid < 64) ldeg[tid] = 0;
    for (int i = tid; i < 64 * CAP / 2; i += 256) ((uint*)llist)[i] = 0;  // zero-pad
    __syncthreads();
    uint start = ofs[k * 256] + bbase[k];
    uint end = (k == NBUCK - 1) ? N_EDGES : (ofs[(k + 1) * 256] + bbase[k + 1]);
    for (uint i = start + tid; i < end; i += 256) {
        uint p = binned[i];
        uint nl = (p >> 16) & 63u;
        uint slot = atomicAdd(&ldeg[nl], 1u);
        if (slot < CAP) llist[(nl << 6) + slot] = (ushort)(p & 0xFFFFu);
    }
    __syncthreads();
    int node0 = k << 6;
    if (tid < 64) deg[node0 + tid] = (int)ldeg[tid];
    uint4* d4 = (uint4*)(list + (size_t)node0 * CAP);
    const uint4* s4 = (const uint4*)llist;
    for (int i = tid; i < 64 * CAP * 2 / 16; i += 256) d4[i] = s4[i];
}

// ---------------- MFMA GEMM: h16 = bf16(A @ W), logits fused as 9th tile ----------------
template <int HEADS, bool ABF16>
__global__ __launch_bounds__(512) void gemm_mfma_kernel(
    const void* __restrict__ Av, const float* __restrict__ W,
    const float* __restrict__ WS,
    ushort* __restrict__ h16, float* __restrict__ a_src, float* __restrict__ a_dst,
    int nrows)
{
    __shared__ ushort Bf[2304 * 8];   // 36 KB
    int tid = threadIdx.x;
    for (int idx = tid; idx < 2304; idx += 512) {
        int t = idx >> 8;
        int rem = idx & 255;
        int kt = rem >> 6, L = rem & 63;
        int col = L & 15;
        int kb = ((L >> 4) << 3) + (kt << 5);
        ushort tmp[8];
        if (t < 8) {
            #pragma unroll
            for (int j = 0; j < 8; j++)
                tmp[j] = f2bf(W[(size_t)(kb + j) * 128 + (t << 4) + col]);
        } else {
            #pragma unroll
            for (int j = 0; j < 8; j++)
                tmp[j] = f2bf(WS[(kb + j) * 16 + col]);
        }
        uint p0 = (uint)tmp[0] | ((uint)tmp[1] << 16);
        uint p1 = (uint)tmp[2] | ((uint)tmp[3] << 16);
        uint p2 = (uint)tmp[4] | ((uint)tmp[5] << 16);
        uint p3 = (uint)tmp[6] | ((uint)tmp[7] << 16);
        *(uint4*)&Bf[idx * 8] = make_uint4(p0, p1, p2, p3);
    }
    __syncthreads();

    int lane = tid & 63;
    int wv = tid >> 6;
    int row0 = (blockIdx.x * 8 + wv) * 16;
    if (row0 >= nrows) return;

    int m = lane & 15, kg = lane >> 4;
    s16x8 afrag[4];
    if (ABF16) {
        const ushort* arow = (const ushort*)Av + (size_t)(row0 + m) * 128 + (kg << 3);
        #pragma unroll
        for (int kt = 0; kt < 4; kt++)
            afrag[kt] = *(const s16x8*)(arow + (kt << 5));
    } else {
        const float* arow = (const float*)Av + (size_t)(row0 + m) * 128 + (kg << 3);
        #pragma unroll
        for (int kt = 0; kt < 4; kt++) {
            float4 f0 = *(const float4*)(arow + (kt << 5));
            float4 f1 = *(const float4*)(arow + (kt << 5) + 4);
            union { s16x8 v; ushort us[8]; } uu;
            uu.us[0] = f2bf(f0.x); uu.us[1] = f2bf(f0.y);
            uu.us[2] = f2bf(f0.z); uu.us[3] = f2bf(f0.w);
            uu.us[4] = f2bf(f1.x); uu.us[5] = f2bf(f1.y);
            uu.us[6] = f2bf(f1.z); uu.us[7] = f2bf(f1.w);
            afrag[kt] = uu.v;
        }
    }

    f32x4 acc[9];
    #pragma unroll
    for (int t = 0; t < 9; t++) acc[t] = (f32x4){0.f, 0.f, 0.f, 0.f};
    #pragma unroll
    for (int t = 0; t < 9; t++) {
        #pragma unroll
        for (int kt = 0; kt < 4; kt++) {
            s16x8 b = *(const s16x8*)&Bf[(((t << 2) + kt) * 64 + lane) * 8];
            acc[t] = __builtin_amdgcn_mfma_f32_16x16x32_bf16(afrag[kt], b, acc[t], 0, 0, 0);
        }
    }

    // D layout: col = lane&15, row = (lane>>4)*4 + r   [m89]
    int colw = lane & 15;
    int rbase = row0 + ((lane >> 4) << 2);
    #pragma unroll
    for (int t = 0; t < 8; t++) {
        #pragma unroll
        for (int r = 0; r < 4; r++)
            h16[(size_t)(rbase + r) * 128 + (t << 4) + colw] = f2bf(acc[t][r]);
    }
    #pragma unroll
    for (int r = 0; r < 4; r++) {
        float v = acc[8][r];
        int row = rbase + r;
        if (HEADS == 8) {
            if (colw < 8) a_src[row * 8 + colw] = v;
            else          a_dst[row * 8 + (colw - 8)] = v;
        } else {
            if (colw == 0)      a_src[row] = v;
            else if (colw == 1) a_dst[row] = v;
        }
    }
}

// ---------------- edge softmax + aggregate. Wave/node; 32-lane-per-edge gather ----------------
// Logits pre-scaled by log2e (folded into WS): exp = exp2. Unnormalized aggregate, rcp at end.
// This is the best-measured structure (40.9 us): chunk=8, all 4 loads of a chunk issued together.
template <int HEADS, bool ELU, bool OUT16>
__global__ __launch_bounds__(256) void agg_kernel(
    const ushort* __restrict__ h16, const ushort* __restrict__ list,
    const int* __restrict__ deg,
    const float* __restrict__ a_src, const float* __restrict__ a_dst,
    const float* __restrict__ bias, void* __restrict__ outv)
{
    __shared__ float w_lds[4][HEADS][65];
    __shared__ int s_lds[4][64];
    __shared__ float sh_l[4][8];
    int lane = threadIdx.x & 63;
    int wv = threadIdx.x >> 6;
    int n = blockIdx.x * 4 + wv;
    int d = min(deg[n], CAP);
    bool valid = lane < d;
    int s = valid ? (int)list[n * CAP + lane] : 0;
    s_lds[wv][lane] = s << 8;           // byte offset of bf16 row

    if (HEADS == 8) {
        float4 u0 = *(const float4*)&a_src[s * 8];
        float4 u1 = *(const float4*)&a_src[s * 8 + 4];
        float4 v0 = *(const float4*)&a_dst[n * 8];
        float4 v1 = *(const float4*)&a_dst[n * 8 + 4];
        float al[8] = {u0.x + v0.x, u0.y + v0.y, u0.z + v0.z, u0.w + v0.w,
                       u1.x + v1.x, u1.y + v1.y, u1.z + v1.z, u1.w + v1.w};
        float eh[8];
        #pragma unroll
        for (int hh = 0; hh < 8; hh++) {
            float a = fmaxf(al[hh], 0.2f * al[hh]);      // leaky_relu(0.2)
            eh[hh] = valid ? exp2f(a) : 0.f;
            w_lds[wv][hh][lane] = eh[hh];
        }
        f32x2 s01 = {eh[0], eh[1]}, s23 = {eh[2], eh[3]};
        f32x2 s45 = {eh[4], eh[5]}, s67 = {eh[6], eh[7]};
        auto lvl = [&](int mm) {
            f32x2 t;
            t.x = __shfl_xor(s01.x, mm); t.y = __shfl_xor(s01.y, mm); s01 = pk_add(s01, t);
            t.x = __shfl_xor(s23.x, mm); t.y = __shfl_xor(s23.y, mm); s23 = pk_add(s23, t);
            t.x = __shfl_xor(s45.x, mm); t.y = __shfl_xor(s45.y, mm); s45 = pk_add(s45, t);
            t.x = __shfl_xor(s67.x, mm); t.y = __shfl_xor(s67.y, mm); s67 = pk_add(s67, t);
        };
        lvl(1); lvl(2); lvl(4); lvl(8);
        if (d > 16) lvl(16);
        if (d > 32) lvl(32);
        if (lane == 0) {
            *(f32x2*)&sh_l[wv][0] = s01; *(f32x2*)&sh_l[wv][2] = s23;
            *(f32x2*)&sh_l[wv][4] = s45; *(f32x2*)&sh_l[wv][6] = s67;
        }
    } else {
        float a = a_src[s] + a_dst[n];
        a = fmaxf(a, 0.2f * a);
        float eh0 = valid ? exp2f(a) : 0.f;
        w_lds[wv][0][lane] = eh0;
        float sh = eh0;
        sh += __shfl_xor(sh, 1); sh += __shfl_xor(sh, 2);
        sh += __shfl_xor(sh, 4); sh += __shfl_xor(sh, 8);
        if (d > 16) sh += __shfl_xor(sh, 16);
        if (d > 32) sh += __shfl_xor(sh, 32);
        if (lane == 0) sh_l[wv][0] = sh;
    }
    // all LDS traffic is wave-private: no barrier needed

    // gather: 32 lanes per edge, 4 channels per lane, 2 edges per round, chunk=8
    int half = lane >> 5;
    int lq = lane & 31;
    int c0 = lq << 2;
    int g = (HEADS == 8) ? (lq >> 2) : 0;
    const char* hp = (const char*)h16 + (c0 << 1);
    f32x2 acc01 = {0.f, 0.f}, acc23 = {0.f, 0.f};
    int d8 = (d + 7) & ~7;
    for (int e0 = 0; e0 < d8; e0 += 8) {
        int soff[4]; float wv4[4]; uint2 u[4];
        #pragma unroll
        for (int r = 0; r < 4; r++) {
            int e = e0 + (r << 1) + half;
            soff[r] = s_lds[wv][e];
            wv4[r] = w_lds[wv][g][e];
        }
        #pragma unroll
        for (int r = 0; r < 4; r++)
            u[r] = *(const uint2*)(hp + soff[r]);
        #pragma unroll
        for (int r = 0; r < 4; r++) {
            f32x2 wp = {wv4[r], wv4[r]};
            f32x2 lo = {bf_lo(u[r].x), bf_hi(u[r].x)};
            f32x2 hi = {bf_lo(u[r].y), bf_hi(u[r].y)};
            acc01 = pk_fma(wp, lo, acc01);
            acc23 = pk_fma(wp, hi, acc23);
        }
    }
    // combine the two edge-halves
    f32x2 t;
    t.x = __shfl_xor(acc01.x, 32); t.y = __shfl_xor(acc01.y, 32); acc01 = pk_add(acc01, t);
    t.x = __shfl_xor(acc23.x, 32); t.y = __shfl_xor(acc23.y, 32); acc23 = pk_add(acc23, t);

    // normalize + bias (+ ELU) + store (lanes 0..31 cover all 128 channels)
    float shv = sh_l[wv][g];
    float r = __builtin_amdgcn_rcpf(shv + 1e-16f);
    f32x2 rr = {r, r};
    acc01 = pk_mul(acc01, rr);
    acc23 = pk_mul(acc23, rr);
    float4 bv = *(const float4*)&bias[c0];
    float o0 = acc01.x + bv.x, o1 = acc01.y + bv.y;
    float o2 = acc23.x + bv.z, o3 = acc23.y + bv.w;
    if (ELU) {
        o0 = o0 > 0.f ? o0 : __expf(o0) - 1.f;
        o1 = o1 > 0.f ? o1 : __expf(o1) - 1.f;
        o2 = o2 > 0.f ? o2 : __expf(o2) - 1.f;
        o3 = o3 > 0.f ? o3 : __expf(o3) - 1.f;
    }
    if (lane < 32) {
        if (OUT16) {
            uint2 pk;
            pk.x = (uint)f2bf(o0) | ((uint)f2bf(o1) << 16);
            pk.y = (uint)f2bf(o2) | ((uint)f2bf(o3) << 16);
            *(uint2*)((ushort*)outv + (size_t)n * 128 + c0) = pk;
        } else {
            *(float4*)((float*)outv + (size_t)n * 128 + c0) = make_float4(o0, o1, o2, o3);
        }
    }
}

extern "C" void kernel_launch(void* const* d_in, const int* in_sizes, int n_in,
                              void* d_out, int out_size, void* d_ws, size_t ws_size,
                              hipStream_t stream)
{
    (void)in_sizes; (void)n_in; (void)out_size; (void)ws_size;
    const float* x   = (const float*)d_in[0];
    const int*   ei  = (const int*)d_in[1];
    const float* W1  = (const float*)d_in[2];
    const float* as1 = (const float*)d_in[3];
    const float* ad1 = (const float*)d_in[4];
    const float* b1  = (const float*)d_in[5];
    const float* W2  = (const float*)d_in[6];
    const float* as2 = (const float*)d_in[7];
    const float* ad2 = (const float*)d_in[8];
    const float* b2  = (const float*)d_in[9];
    float* out = (float*)d_out;
    const int* srcv = ei;
    const int* dstv = ei + N_EDGES;

    char* ws = (char*)d_ws;
    size_t off = 0;
    auto alloc = [&](size_t bytes) {
        void* p = ws + off;
        off += (bytes + 255) & ~(size_t)255;
        return p;
    };
    ushort* h1_16 = (ushort*)alloc((size_t)N_NODES * 128 * 2);
    ushort* h2_16 = (ushort*)alloc((size_t)N_NODES * 128 * 2);
    ushort* h1b   = (ushort*)alloc((size_t)N_NODES * 128 * 2);   // bf16 inter-layer act
    float*  asrc1 = (float*)alloc((size_t)N_NODES * 8 * 4);
    float*  adst1 = (float*)alloc((size_t)N_NODES * 8 * 4);
    float*  asrc2 = (float*)alloc((size_t)N_NODES * 4);
    float*  adst2 = (float*)alloc((size_t)N_NODES * 4);
    int*    degp  = (int*)alloc((size_t)NODES_PAD * 4);
    ushort* list  = (ushort*)alloc((size_t)NODES_PAD * CAP * 2);
    float*  WS1   = (float*)alloc(128 * 16 * 4);
    float*  WS2   = (float*)alloc(128 * 16 * 4);
    // bin scratch aliases into h1b (fully consumed before agg1 writes h1b)
    uint* binned = (uint*)h1b;                       // 3.2 MB
    uint* counts = binned + N_EDGES;                 // 800 KB (NBUCK*BBLK)
    uint* ofsp   = counts + NBUCK * BBLK;            // 800 KB
    uint* bsum   = ofsp + NBUCK * BBLK;              // ~3 KB
    uint* bbase  = bsum + NBUCK;                     // ~3 KB

    const int NG = (N_NODES + 3) / 4;              // 12500
    const int GB = (N_NODES / 16 + 7) / 8;         // 391 blocks of 8 waves

    bin_count_kernel<<<BBLK, 256, 0, stream>>>(dstv, counts);
    scan1_kernel<<<NBUCK, 256, 0, stream>>>(counts, ofsp, bsum);
    scan2_prep_kernel<<<17, 256, 0, stream>>>(bsum, bbase, W1, as1, ad1, W2, as2, ad2, WS1, WS2);
    bin_scatter_kernel<<<BBLK, 256, 0, stream>>>(srcv, dstv, ofsp, bbase, binned);
    build_kernel<<<NBUCK, 256, 0, stream>>>(binned, ofsp, bbase, degp, list);

    gemm_mfma_kernel<8, false><<<GB, 512, 0, stream>>>(x, W1, WS1, h1_16, asrc1, adst1, N_NODES);
    agg_kernel<8, true, true><<<NG, 256, 0, stream>>>(h1_16, list, degp, asrc1, adst1, b1, h1b);

    gemm_mfma_kernel<1, true><<<GB, 512, 0, stream>>>(h1b, W2, WS2, h2_16, asrc2, adst2, N_NODES);
    agg_kernel<1, false, false><<<NG, 256, 0, stream>>>(h2_16, list, degp, asrc2, adst2, b2, out);
}